// Round 6
// baseline (479.413 us; speedup 1.0000x reference)
//
#include <hip/hip_runtime.h>

// Problem constants (match reference): B=128, D_IN=512, D_H=1024, D_OUT=512
constexpr int B_    = 128;
constexpr int D_IN  = 512;
constexpr int D_H   = 1024;
constexpr int D_OUT = 512;

// Native clang vector type — __builtin_nontemporal_load requires a pointer to
// integer/float/vector-of-such; HIP's float4 is a class and is rejected.
typedef float f32x4 __attribute__((ext_vector_type(4)));

// Non-temporal 16B load: weights are streamed once (512 MB >> 256 MB L3),
// keep them from evicting the reused x/h vectors.
__device__ __forceinline__ f32x4 nt_load4(const float* p) {
  return __builtin_nontemporal_load(reinterpret_cast<const f32x4*>(p));
}

// Layer 1: h[b,r] = relu( dot(W1[b,r,:], x[b,:]) + b1[b,r] )
// One 64-lane wave per output element. Row length 512 -> 2 float4 iters/lane.
__global__ __launch_bounds__(256) void gemv_relu_l1(
    const float* __restrict__ x, const float* __restrict__ W1,
    const float* __restrict__ b1, float* __restrict__ h) {
  const int wave = blockIdx.x * (blockDim.x >> 6) + (threadIdx.x >> 6);
  const int lane = threadIdx.x & 63;
  const int b = wave >> 10;        // / D_H
  const float* wrow = W1 + (size_t)wave * D_IN;
  const f32x4* xrow = reinterpret_cast<const f32x4*>(x + (size_t)b * D_IN);
  float s = 0.f;
#pragma unroll
  for (int it = 0; it < D_IN / 256; ++it) {
    f32x4 w = nt_load4(wrow + (it * 64 + lane) * 4);
    f32x4 xv = xrow[it * 64 + lane];
    s += w.x * xv.x + w.y * xv.y + w.z * xv.z + w.w * xv.w;
  }
#pragma unroll
  for (int off = 32; off >= 1; off >>= 1) s += __shfl_down(s, off);
  if (lane == 0) {
    float v = s + b1[wave];
    h[wave] = v > 0.f ? v : 0.f;
  }
}

// Layer 2: out[b,o] = dot(W2[b,o,:], h[b,:]) + b2[b,o]
// Row length 1024 -> 4 float4 iters/lane.
__global__ __launch_bounds__(256) void gemv_l2(
    const float* __restrict__ h, const float* __restrict__ W2,
    const float* __restrict__ b2, float* __restrict__ out) {
  const int wave = blockIdx.x * (blockDim.x >> 6) + (threadIdx.x >> 6);
  const int lane = threadIdx.x & 63;
  const int b = wave >> 9;         // / D_OUT
  const float* wrow = W2 + (size_t)wave * D_H;
  const f32x4* hrow = reinterpret_cast<const f32x4*>(h + (size_t)b * D_H);
  float s = 0.f;
#pragma unroll
  for (int it = 0; it < D_H / 256; ++it) {
    f32x4 w = nt_load4(wrow + (it * 64 + lane) * 4);
    f32x4 hv = hrow[it * 64 + lane];
    s += w.x * hv.x + w.y * hv.y + w.z * hv.z + w.w * hv.w;
  }
#pragma unroll
  for (int off = 32; off >= 1; off >>= 1) s += __shfl_down(s, off);
  if (lane == 0) {
    out[wave] = s + b2[wave];
  }
}

extern "C" void kernel_launch(void* const* d_in, const int* in_sizes, int n_in,
                              void* d_out, int out_size, void* d_ws, size_t ws_size,
                              hipStream_t stream) {
  const float* x  = (const float*)d_in[0];
  const float* W1 = (const float*)d_in[1];
  const float* b1 = (const float*)d_in[2];
  const float* W2 = (const float*)d_in[3];
  const float* b2 = (const float*)d_in[4];
  float* out = (float*)d_out;
  float* h   = (float*)d_ws;   // B*D_H floats = 512 KiB

  // Layer 1: B*D_H = 131072 outputs, 4 waves/block -> 32768 blocks
  gemv_relu_l1<<<(B_ * D_H) / 4, 256, 0, stream>>>(x, W1, b1, h);
  // Layer 2: B*D_OUT = 65536 outputs -> 16384 blocks
  gemv_l2<<<(B_ * D_OUT) / 4, 256, 0, stream>>>(h, W2, b2, out);
}